// Round 6
// baseline (233.586 us; speedup 1.0000x reference)
//
#include <hip/hip_runtime.h>
#include <hip/hip_fp16.h>

#define SEQ 2048
#define DIM 512

typedef __attribute__((ext_vector_type(8))) short short8;
typedef __attribute__((ext_vector_type(4))) float f32x4;
typedef _Float16 h8 __attribute__((ext_vector_type(8)));
typedef _Float16 h4 __attribute__((ext_vector_type(4)));

#define MFMA16(a, b, c) __builtin_amdgcn_mfma_f32_16x16x32_f16((a), (b), (c), 0, 0, 0)

#define GLOAD_LDS16(g, l)                                                              \
    __builtin_amdgcn_global_load_lds(                                                  \
        (const __attribute__((address_space(1))) unsigned int*)(g),                    \
        (__attribute__((address_space(3))) unsigned int*)(l), 16, 0, 0)

// ---- stage one 128x32 f16 tile (8KB) into linear LDS (async, swizzled src) --
__device__ __forceinline__ void stageT(const _Float16* __restrict__ gbase, int pitch_h,
                                       char* ldsbase, int wid, int lane) {
#pragma unroll
    for (int j = 0; j < 2; ++j) {
        int c = (j * 4 + wid) * 64 + lane;
        int row = c >> 2, s = c & 3;
        int col16 = s ^ ((row >> 1) & 3);   // inverse swizzle on global source
        const char* g = (const char*)gbase + (size_t)row * (pitch_h * 2) + col16 * 16;
        GLOAD_LDS16(g, ldsbase + (j * 4 + wid) * 1024);
    }
}
__device__ __forceinline__ h8 fragswz(const _Float16* lds, int row, int g) {
    int g2 = g ^ ((row >> 1) & 3);
    return *(const h8*)((const char*)lds + row * 64 + g2 * 16);
}

// ============ unified 128x128 GEMM engine, 3-buf counted-vmcnt pipeline =====
// MODE 0: proj  C[16384,1536] = xh @ W'  (W' = [Wh;Wl] stacked, virtual K=1024)
// MODE 1: qk    S[b][2048,2048] = Q @ K^T (K=512)
// MODE 2: pv    out[b][2048,512] = P @ V^T (K=2048)
template <int MODE>
__global__ __launch_bounds__(256) void gemmc(
    const _Float16* __restrict__ A, const _Float16* __restrict__ B,
    const float* __restrict__ bq, const float* __restrict__ bk,
    const float* __restrict__ bv,
    _Float16* __restrict__ oq, _Float16* __restrict__ ok, _Float16* __restrict__ ovt,
    float* __restrict__ of, int bat0) {
    __shared__ _Float16 abuf[3][128 * 32], bbuf[3][128 * 32];
    constexpr int T  = (MODE == 0) ? 32 : (MODE == 1) ? 16 : 64;
    constexpr int PA = (MODE == 0) ? 512 : (MODE == 1) ? 512 : 4096;
    constexpr int PB = (MODE == 0) ? 1024 : (MODE == 1) ? 512 : 2048;

    int tid = threadIdx.x, wid = tid >> 6, lane = tid & 63, r = lane & 15, g = lane >> 4;
    int mw = wid >> 1, nw = wid & 1;
    int m0 = blockIdx.x * 128, n0 = blockIdx.y * 128, bz = blockIdx.z;

    const _Float16 *Ab, *Bb;
    if (MODE == 0) {
        Ab = A + (size_t)m0 * 512;
        Bb = B + (size_t)n0 * 1024;
    } else if (MODE == 1) {
        int b = bat0 + bz;
        Ab = A + ((size_t)(b * SEQ) + m0) * 512;
        Bb = B + ((size_t)(b * SEQ) + n0) * 512;
    } else {
        int b = bat0 + bz;
        Ab = A + (size_t)bz * (SEQ * 4096) + (size_t)m0 * 4096;
        Bb = B + (size_t)b * (512 * SEQ) + (size_t)n0 * 2048;
    }
    auto acol = [&](int t) { return (MODE == 0) ? ((t & 15) * 32) : (t * 32); };

    f32x4 acc[4][4];
#pragma unroll
    for (int m = 0; m < 4; ++m)
#pragma unroll
        for (int n = 0; n < 4; ++n) acc[m][n] = (f32x4)(0.0f);

    // prologue: stage tiles 0 and 1
    stageT(Ab + acol(0), PA, (char*)abuf[0], wid, lane);
    stageT(Bb + 0, PB, (char*)bbuf[0], wid, lane);
    stageT(Ab + acol(1), PA, (char*)abuf[1], wid, lane);
    stageT(Bb + 32, PB, (char*)bbuf[1], wid, lane);
    asm volatile("s_waitcnt vmcnt(4)" ::: "memory");   // tile 0 landed
    __builtin_amdgcn_s_barrier();

    const _Float16* a0 = abuf[0]; const _Float16* a1 = abuf[1]; const _Float16* a2 = abuf[2];
    const _Float16* b0 = bbuf[0]; const _Float16* b1 = bbuf[1]; const _Float16* b2 = bbuf[2];

    for (int t = 0; t < T; ++t) {
        if (t + 2 < T) {   // issue prefetch for t+2 (2 tiles ahead)
            stageT(Ab + acol(t + 2), PA, (char*)const_cast<_Float16*>(a2), wid, lane);
            stageT(Bb + (t + 2) * 32, PB, (char*)const_cast<_Float16*>(b2), wid, lane);
        }
        h8 af[4], bf[4];
#pragma unroll
        for (int m = 0; m < 4; ++m) af[m] = fragswz(a0, mw * 64 + m * 16 + r, g);
#pragma unroll
        for (int n = 0; n < 4; ++n) bf[n] = fragswz(b0, nw * 64 + n * 16 + r, g);
#pragma unroll
        for (int m = 0; m < 4; ++m)
#pragma unroll
            for (int n = 0; n < 4; ++n)
                acc[m][n] = MFMA16(af[m], bf[n], acc[m][n]);
        // counted wait: keep t+2's 4 loads in flight, ensure t+1 landed
        if (t + 2 < T) asm volatile("s_waitcnt vmcnt(4)" ::: "memory");
        else if (t + 1 < T) asm volatile("s_waitcnt vmcnt(0)" ::: "memory");
        if (t + 1 < T) __builtin_amdgcn_s_barrier();
        const _Float16* ta = a0; a0 = a1; a1 = a2; a2 = ta;
        const _Float16* tb = b0; b0 = b1; b1 = b2; b2 = tb;
    }

    // ---- epilogue ----
    if (MODE == 0) {
        int p = n0 >> 9;
        int ncl = n0 & 511;
        const float* bias = (p == 0) ? bq : (p == 1) ? bk : bv;
#pragma unroll
        for (int n = 0; n < 4; ++n) {
            int col = ncl + nw * 64 + n * 16 + r;
            float bi = bias[col];
#pragma unroll
            for (int m = 0; m < 4; ++m) {
                int grow0 = m0 + mw * 64 + m * 16 + 4 * g;
                if (p == 0) {
                    for (int reg = 0; reg < 4; ++reg)
                        oq[(size_t)(grow0 + reg) * 512 + col] =
                            (_Float16)(acc[m][n][reg] + bi);
                } else if (p == 1) {
                    for (int reg = 0; reg < 4; ++reg)
                        ok[(size_t)(grow0 + reg) * 512 + col] =
                            (_Float16)(acc[m][n][reg] + bi);
                } else {
                    int b = grow0 >> 11, s0 = grow0 & 2047;
                    h4 pv;
                    pv[0] = (_Float16)(acc[m][n][0] + bi);
                    pv[1] = (_Float16)(acc[m][n][1] + bi);
                    pv[2] = (_Float16)(acc[m][n][2] + bi);
                    pv[3] = (_Float16)(acc[m][n][3] + bi);
                    *(h4*)(&ovt[(size_t)b * (512 * 2048) + (size_t)col * 2048 + s0]) = pv;
                }
            }
        }
    } else if (MODE == 1) {
        float* sb = of + (size_t)bz * (SEQ * (size_t)SEQ);
#pragma unroll
        for (int n = 0; n < 4; ++n) {
            int col = n0 + nw * 64 + n * 16 + r;
#pragma unroll
            for (int m = 0; m < 4; ++m) {
                int grow0 = m0 + mw * 64 + m * 16 + 4 * g;
                for (int reg = 0; reg < 4; ++reg)
                    sb[(size_t)(grow0 + reg) * SEQ + col] = acc[m][n][reg];
            }
        }
    } else {
        int b = bat0 + bz;
#pragma unroll
        for (int n = 0; n < 4; ++n) {
            int col = n0 + nw * 64 + n * 16 + r;
#pragma unroll
            for (int m = 0; m < 4; ++m) {
                int grow0 = m0 + mw * 64 + m * 16 + 4 * g;
                for (int reg = 0; reg < 4; ++reg)
                    of[(size_t)(b * SEQ + grow0 + reg) * 512 + col] = acc[m][n][reg];
            }
        }
    }
}

// ---------------- K0a: split W -> f16 hi/lo, stacked-K, transposed ----------
__global__ __launch_bounds__(256) void k0a_splitw(
    const float* __restrict__ Wq, const float* __restrict__ Wk, const float* __restrict__ Wv,
    _Float16* __restrict__ wstk) {
    int idx = blockIdx.x * 256 + threadIdx.x;   // [0, 3*512*512)
    int p = idx >> 18;
    int rem = idx & 262143;
    int k = rem >> 9, n = rem & 511;
    const float* W = (p == 0) ? Wq : (p == 1) ? Wk : Wv;
    float w = W[rem];
    _Float16 h = (_Float16)w;
    size_t base = (size_t)(p * 512 + n) * 1024;
    wstk[base + k] = h;
    wstk[base + 512 + k] = (_Float16)(w - (float)h);
}

// ---------------- K0b: x -> f16 ---------------------------------------------
__global__ __launch_bounds__(256) void k0b_splitx(
    const float* __restrict__ x, _Float16* __restrict__ xh) {
    size_t i = (size_t)(blockIdx.x * 256 + threadIdx.x) * 4;
    float4 v = *(const float4*)(x + i);
    h4 h;
    h[0] = (_Float16)v.x; h[1] = (_Float16)v.y;
    h[2] = (_Float16)v.z; h[3] = (_Float16)v.w;
    *(h4*)(xh + i) = h;
}

// ---------------- K3: row softmax, in-place P(f16) over S(f32) --------------
__global__ __launch_bounds__(256) void k3_softmax(float* __restrict__ sbuf) {
    size_t row = blockIdx.x;
    float* srow = sbuf + row * SEQ;
    int tid = threadIdx.x, lane = tid & 63, wid = tid >> 6;
    float4 v0 = *(const float4*)(srow + tid * 8);
    float4 v1 = *(const float4*)(srow + tid * 8 + 4);
    float m = fmaxf(fmaxf(fmaxf(v0.x, v0.y), fmaxf(v0.z, v0.w)),
                    fmaxf(fmaxf(v1.x, v1.y), fmaxf(v1.z, v1.w)));
    for (int d = 1; d < 64; d <<= 1) m = fmaxf(m, __shfl_xor(m, d));
    __shared__ float red1[4], red2[4];
    if (lane == 0) red1[wid] = m;
    __syncthreads();
    m = fmaxf(fmaxf(red1[0], red1[1]), fmaxf(red1[2], red1[3]));
    float e[8];
    e[0] = __expf(v0.x - m); e[1] = __expf(v0.y - m);
    e[2] = __expf(v0.z - m); e[3] = __expf(v0.w - m);
    e[4] = __expf(v1.x - m); e[5] = __expf(v1.y - m);
    e[6] = __expf(v1.z - m); e[7] = __expf(v1.w - m);
    float s = ((e[0] + e[1]) + (e[2] + e[3])) + ((e[4] + e[5]) + (e[6] + e[7]));
    for (int d = 1; d < 64; d <<= 1) s += __shfl_xor(s, d);
    if (lane == 0) red2[wid] = s;
    __syncthreads();
    s = (red2[0] + red2[1]) + (red2[2] + red2[3]);
    float inv = 1.0f / s;
    h8 ph;
    for (int j = 0; j < 8; ++j) ph[j] = (_Float16)(e[j] * inv);
    *(h8*)((char*)srow + (size_t)tid * 16) = ph;   // P row: first 4KB of S row
}

// ---------------------------------------------------------------------------
extern "C" void kernel_launch(void* const* d_in, const int* in_sizes, int n_in,
                              void* d_out, int out_size, void* d_ws, size_t ws_size,
                              hipStream_t stream) {
    const float* x  = (const float*)d_in[0];
    const float* Wq = (const float*)d_in[1];
    const float* bq = (const float*)d_in[2];
    const float* Wk = (const float*)d_in[3];
    const float* bk = (const float*)d_in[4];
    const float* Wv = (const float*)d_in[5];
    const float* bv = (const float*)d_in[6];
    float* out = (float*)d_out;

    char* ws = (char*)d_ws;
    const size_t QSZ = 16777216;   // 16384*512*2B (also = one batch of S fp32)
    _Float16* wstk = (_Float16*)(ws);                         // 3MB stacked W'
    _Float16* xh = (_Float16*)(ws + 3145728);
    _Float16* qh = (_Float16*)(ws + 3145728 + 1 * QSZ);
    _Float16* kh = (_Float16*)(ws + 3145728 + 2 * QSZ);
    _Float16* vt = (_Float16*)(ws + 3145728 + 3 * QSZ);
    const size_t sbase = 3145728 + 4 * QSZ;          // 70,254,592

    k0a_splitw<<<3072, 256, 0, stream>>>(Wq, Wk, Wv, wstk);
    k0b_splitx<<<8192, 256, 0, stream>>>(x, xh);
    gemmc<0><<<dim3(128, 12), 256, 0, stream>>>(xh, wstk, bq, bk, bv,
                                                qh, kh, vt, nullptr, 0);

    size_t avail = (ws_size > sbase) ? (ws_size - sbase) : 0;
    int chunk = (int)(avail / QSZ);
    if (chunk < 1) chunk = 1;
    if (chunk > 8) chunk = 8;
    float* sc = (float*)(ws + sbase);
    for (int b0 = 0; b0 < 8; b0 += chunk) {
        int nb = (8 - b0 < chunk) ? (8 - b0) : chunk;
        gemmc<1><<<dim3(16, 16, nb), 256, 0, stream>>>(qh, kh, nullptr, nullptr, nullptr,
                                                       nullptr, nullptr, nullptr, sc, b0);
        k3_softmax<<<dim3(nb * SEQ), 256, 0, stream>>>(sc);
        gemmc<2><<<dim3(16, 4, nb), 256, 0, stream>>>((const _Float16*)sc, vt,
                                                      nullptr, nullptr, nullptr,
                                                      nullptr, nullptr, nullptr, out, b0);
    }
}

// Round 7
// 210.143 us; speedup vs baseline: 1.1116x; 1.1116x over previous
//
#include <hip/hip_runtime.h>
#include <hip/hip_fp16.h>

#define SEQ 2048
#define DIM 512

typedef __attribute__((ext_vector_type(8))) short short8;
typedef __attribute__((ext_vector_type(4))) float f32x4;
typedef _Float16 h8 __attribute__((ext_vector_type(8)));
typedef _Float16 h4 __attribute__((ext_vector_type(4)));

#define MFMA16(a, b, c) __builtin_amdgcn_mfma_f32_16x16x32_f16((a), (b), (c), 0, 0, 0)

#define GLOAD_LDS16(g, l)                                                              \
    __builtin_amdgcn_global_load_lds(                                                  \
        (const __attribute__((address_space(1))) unsigned int*)(g),                    \
        (__attribute__((address_space(3))) unsigned int*)(l), 16, 0, 0)

// ============ unified 128x128 GEMM engine, lane-static fully-unrolled =======
// 3 LDS buffers, prefetch distance 2, counted vmcnt (never 0 mid-loop).
// MODE 0: proj  C[16384,1536] = xh @ W'  (W' = [Wh;Wl] stacked, virtual K=1024)
// MODE 1: qk    S[b][2048,2048] = Q @ K^T (K=512)
// MODE 2: pv    out[b][2048,512] = P @ V^T (K=2048)
template <int MODE>
__global__ __launch_bounds__(256) void gemmc(
    const _Float16* __restrict__ A, const _Float16* __restrict__ B,
    const float* __restrict__ bq, const float* __restrict__ bk,
    const float* __restrict__ bv,
    _Float16* __restrict__ oq, _Float16* __restrict__ ok, _Float16* __restrict__ ovt,
    float* __restrict__ of, int bat0) {
    __shared__ char sm[3 * 16384];   // buf b: A at b*16384, B at b*16384+8192
    constexpr int T  = (MODE == 0) ? 32 : (MODE == 1) ? 16 : 64;
    constexpr int PA = (MODE == 0) ? 512 : (MODE == 1) ? 512 : 4096;
    constexpr int PB = (MODE == 0) ? 1024 : (MODE == 1) ? 512 : 2048;

    int tid = threadIdx.x, wid = tid >> 6, lane = tid & 63, r = lane & 15, g = lane >> 4;
    int mw = wid >> 1, nw = wid & 1;
    int m0 = blockIdx.x * 128, n0 = blockIdx.y * 128, bz = blockIdx.z;

    const _Float16 *Ab, *Bb;
    if (MODE == 0) {
        Ab = A + (size_t)m0 * 512;
        Bb = B + (size_t)n0 * 1024;
    } else if (MODE == 1) {
        int b = bat0 + bz;
        Ab = A + ((size_t)(b * SEQ) + m0) * 512;
        Bb = B + ((size_t)(b * SEQ) + n0) * 512;
    } else {
        int b = bat0 + bz;
        Ab = A + (size_t)bz * (SEQ * 4096) + (size_t)m0 * 4096;
        Bb = B + (size_t)b * (512 * SEQ) + (size_t)n0 * 2048;
    }

    // ---- lane-static staging addresses (computed once) ----
    const char* gA[2];
    const char* gB[2];
    int ldsw[2];
#pragma unroll
    for (int j = 0; j < 2; ++j) {
        int c = (j * 4 + wid) * 64 + lane;
        int row = c >> 2, s = c & 3;
        int col16 = s ^ ((row >> 1) & 3);   // inverse swizzle on global source
        gA[j] = (const char*)Ab + (size_t)row * (PA * 2) + col16 * 16;
        gB[j] = (const char*)Bb + (size_t)row * (PB * 2) + col16 * 16;
        ldsw[j] = (j * 4 + wid) * 1024;
    }
    // ---- lane-static fragment read offsets ----
    int offA[4], offB[4];
#pragma unroll
    for (int m = 0; m < 4; ++m) {
        int rowA = mw * 64 + m * 16 + r;
        offA[m] = rowA * 64 + ((g ^ ((rowA >> 1) & 3)) * 16);
        int rowB = nw * 64 + m * 16 + r;
        offB[m] = rowB * 64 + ((g ^ ((rowB >> 1) & 3)) * 16);
    }

    f32x4 acc[4][4];
#pragma unroll
    for (int m = 0; m < 4; ++m)
#pragma unroll
        for (int n = 0; n < 4; ++n) acc[m][n] = (f32x4)(0.0f);

    // stage tile t into buffer b (4 async loads); k-offsets are constants
    auto STG = [&](int t, int b) {
        int ka = (MODE == 0) ? ((t & 15) * 64) : (t * 64);
        int kb = t * 64;
        char* dA = sm + b * 16384;
        char* dB = sm + b * 16384 + 8192;
        GLOAD_LDS16(gA[0] + ka, dA + ldsw[0]);
        GLOAD_LDS16(gA[1] + ka, dA + ldsw[1]);
        GLOAD_LDS16(gB[0] + kb, dB + ldsw[0]);
        GLOAD_LDS16(gB[1] + kb, dB + ldsw[1]);
    };

    // prologue: tiles 0 and 1
    STG(0, 0);
    STG(1, 1);
    asm volatile("s_waitcnt vmcnt(4)" ::: "memory");   // tile 0 landed
    __builtin_amdgcn_s_barrier();

#pragma unroll
    for (int t = 0; t < T; ++t) {
        const int buf = t % 3;
        if (t + 2 < T) STG(t + 2, (t + 2) % 3);
        const char* bA = sm + buf * 16384;
        const char* bB = sm + buf * 16384 + 8192;
        h8 af[4], bf[4];
#pragma unroll
        for (int m = 0; m < 4; ++m) af[m] = *(const h8*)(bA + offA[m]);
#pragma unroll
        for (int n = 0; n < 4; ++n) bf[n] = *(const h8*)(bB + offB[n]);
#pragma unroll
        for (int m = 0; m < 4; ++m)
#pragma unroll
            for (int n = 0; n < 4; ++n)
                acc[m][n] = MFMA16(af[m], bf[n], acc[m][n]);
        // counted wait: t+2's 4 loads stay in flight; t+1 must have landed
        if (t + 2 < T) asm volatile("s_waitcnt vmcnt(4)" ::: "memory");
        else if (t + 1 < T) asm volatile("s_waitcnt vmcnt(0)" ::: "memory");
        if (t + 1 < T) __builtin_amdgcn_s_barrier();
    }

    // ---- epilogue ----
    if (MODE == 0) {
        int p = n0 >> 9;
        int ncl = n0 & 511;
        const float* bias = (p == 0) ? bq : (p == 1) ? bk : bv;
#pragma unroll
        for (int n = 0; n < 4; ++n) {
            int col = ncl + nw * 64 + n * 16 + r;
            float bi = bias[col];
#pragma unroll
            for (int m = 0; m < 4; ++m) {
                int grow0 = m0 + mw * 64 + m * 16 + 4 * g;
                if (p == 0) {
                    for (int reg = 0; reg < 4; ++reg)
                        oq[(size_t)(grow0 + reg) * 512 + col] =
                            (_Float16)(acc[m][n][reg] + bi);
                } else if (p == 1) {
                    for (int reg = 0; reg < 4; ++reg)
                        ok[(size_t)(grow0 + reg) * 512 + col] =
                            (_Float16)(acc[m][n][reg] + bi);
                } else {
                    int b = grow0 >> 11, s0 = grow0 & 2047;
                    h4 pv;
                    pv[0] = (_Float16)(acc[m][n][0] + bi);
                    pv[1] = (_Float16)(acc[m][n][1] + bi);
                    pv[2] = (_Float16)(acc[m][n][2] + bi);
                    pv[3] = (_Float16)(acc[m][n][3] + bi);
                    *(h4*)(&ovt[(size_t)b * (512 * 2048) + (size_t)col * 2048 + s0]) = pv;
                }
            }
        }
    } else if (MODE == 1) {
        float* sb = of + (size_t)bz * (SEQ * (size_t)SEQ);
#pragma unroll
        for (int n = 0; n < 4; ++n) {
            int col = n0 + nw * 64 + n * 16 + r;
#pragma unroll
            for (int m = 0; m < 4; ++m) {
                int grow0 = m0 + mw * 64 + m * 16 + 4 * g;
                for (int reg = 0; reg < 4; ++reg)
                    sb[(size_t)(grow0 + reg) * SEQ + col] = acc[m][n][reg];
            }
        }
    } else {
        int b = bat0 + bz;
#pragma unroll
        for (int n = 0; n < 4; ++n) {
            int col = n0 + nw * 64 + n * 16 + r;
#pragma unroll
            for (int m = 0; m < 4; ++m) {
                int grow0 = m0 + mw * 64 + m * 16 + 4 * g;
                for (int reg = 0; reg < 4; ++reg)
                    of[(size_t)(b * SEQ + grow0 + reg) * 512 + col] = acc[m][n][reg];
            }
        }
    }
}

// ---------------- K0a: split W -> f16 hi/lo, stacked-K, transposed ----------
__global__ __launch_bounds__(256) void k0a_splitw(
    const float* __restrict__ Wq, const float* __restrict__ Wk, const float* __restrict__ Wv,
    _Float16* __restrict__ wstk) {
    int idx = blockIdx.x * 256 + threadIdx.x;   // [0, 3*512*512)
    int p = idx >> 18;
    int rem = idx & 262143;
    int k = rem >> 9, n = rem & 511;
    const float* W = (p == 0) ? Wq : (p == 1) ? Wk : Wv;
    float w = W[rem];
    _Float16 h = (_Float16)w;
    size_t base = (size_t)(p * 512 + n) * 1024;
    wstk[base + k] = h;
    wstk[base + 512 + k] = (_Float16)(w - (float)h);
}

// ---------------- K0b: x -> f16 ---------------------------------------------
__global__ __launch_bounds__(256) void k0b_splitx(
    const float* __restrict__ x, _Float16* __restrict__ xh) {
    size_t i = (size_t)(blockIdx.x * 256 + threadIdx.x) * 4;
    float4 v = *(const float4*)(x + i);
    h4 h;
    h[0] = (_Float16)v.x; h[1] = (_Float16)v.y;
    h[2] = (_Float16)v.z; h[3] = (_Float16)v.w;
    *(h4*)(xh + i) = h;
}

// ---------------- K3: row softmax, in-place P(f16) over S(f32) --------------
__global__ __launch_bounds__(256) void k3_softmax(float* __restrict__ sbuf) {
    size_t row = blockIdx.x;
    float* srow = sbuf + row * SEQ;
    int tid = threadIdx.x, lane = tid & 63, wid = tid >> 6;
    float4 v0 = *(const float4*)(srow + tid * 8);
    float4 v1 = *(const float4*)(srow + tid * 8 + 4);
    float m = fmaxf(fmaxf(fmaxf(v0.x, v0.y), fmaxf(v0.z, v0.w)),
                    fmaxf(fmaxf(v1.x, v1.y), fmaxf(v1.z, v1.w)));
    for (int d = 1; d < 64; d <<= 1) m = fmaxf(m, __shfl_xor(m, d));
    __shared__ float red1[4], red2[4];
    if (lane == 0) red1[wid] = m;
    __syncthreads();
    m = fmaxf(fmaxf(red1[0], red1[1]), fmaxf(red1[2], red1[3]));
    float e[8];
    e[0] = __expf(v0.x - m); e[1] = __expf(v0.y - m);
    e[2] = __expf(v0.z - m); e[3] = __expf(v0.w - m);
    e[4] = __expf(v1.x - m); e[5] = __expf(v1.y - m);
    e[6] = __expf(v1.z - m); e[7] = __expf(v1.w - m);
    float s = ((e[0] + e[1]) + (e[2] + e[3])) + ((e[4] + e[5]) + (e[6] + e[7]));
    for (int d = 1; d < 64; d <<= 1) s += __shfl_xor(s, d);
    if (lane == 0) red2[wid] = s;
    __syncthreads();
    s = (red2[0] + red2[1]) + (red2[2] + red2[3]);
    float inv = 1.0f / s;
    h8 ph;
    for (int j = 0; j < 8; ++j) ph[j] = (_Float16)(e[j] * inv);
    *(h8*)((char*)srow + (size_t)tid * 16) = ph;   // P row: first 4KB of S row
}

// ---------------------------------------------------------------------------
extern "C" void kernel_launch(void* const* d_in, const int* in_sizes, int n_in,
                              void* d_out, int out_size, void* d_ws, size_t ws_size,
                              hipStream_t stream) {
    const float* x  = (const float*)d_in[0];
    const float* Wq = (const float*)d_in[1];
    const float* bq = (const float*)d_in[2];
    const float* Wk = (const float*)d_in[3];
    const float* bk = (const float*)d_in[4];
    const float* Wv = (const float*)d_in[5];
    const float* bv = (const float*)d_in[6];
    float* out = (float*)d_out;

    char* ws = (char*)d_ws;
    const size_t QSZ = 16777216;   // 16384*512*2B (also = one batch of S fp32)
    _Float16* wstk = (_Float16*)(ws);                         // 3MB stacked W'
    _Float16* xh = (_Float16*)(ws + 3145728);
    _Float16* qh = (_Float16*)(ws + 3145728 + 1 * QSZ);
    _Float16* kh = (_Float16*)(ws + 3145728 + 2 * QSZ);
    _Float16* vt = (_Float16*)(ws + 3145728 + 3 * QSZ);
    const size_t sbase = 3145728 + 4 * QSZ;          // 70,254,592

    k0a_splitw<<<3072, 256, 0, stream>>>(Wq, Wk, Wv, wstk);
    k0b_splitx<<<8192, 256, 0, stream>>>(x, xh);
    gemmc<0><<<dim3(128, 12), 256, 0, stream>>>(xh, wstk, bq, bk, bv,
                                                qh, kh, vt, nullptr, 0);

    size_t avail = (ws_size > sbase) ? (ws_size - sbase) : 0;
    int chunk = (int)(avail / QSZ);
    if (chunk < 1) chunk = 1;
    if (chunk > 8) chunk = 8;
    float* sc = (float*)(ws + sbase);
    for (int b0 = 0; b0 < 8; b0 += chunk) {
        int nb = (8 - b0 < chunk) ? (8 - b0) : chunk;
        gemmc<1><<<dim3(16, 16, nb), 256, 0, stream>>>(qh, kh, nullptr, nullptr, nullptr,
                                                       nullptr, nullptr, nullptr, sc, b0);
        k3_softmax<<<dim3(nb * SEQ), 256, 0, stream>>>(sc);
        gemmc<2><<<dim3(16, 4, nb), 256, 0, stream>>>((const _Float16*)sc, vt,
                                                      nullptr, nullptr, nullptr,
                                                      nullptr, nullptr, nullptr, out, b0);
    }
}

// Round 8
// 189.097 us; speedup vs baseline: 1.2353x; 1.1113x over previous
//
#include <hip/hip_runtime.h>
#include <hip/hip_fp16.h>

#define SEQ 2048
#define DIM 512

typedef __attribute__((ext_vector_type(8))) short short8;
typedef __attribute__((ext_vector_type(4))) float f32x4;
typedef _Float16 h8 __attribute__((ext_vector_type(8)));
typedef _Float16 h4 __attribute__((ext_vector_type(4)));

#define MFMA16(a, b, c) __builtin_amdgcn_mfma_f32_16x16x32_f16((a), (b), (c), 0, 0, 0)

#define GLOAD_LDS16(g, l)                                                              \
    __builtin_amdgcn_global_load_lds(                                                  \
        (const __attribute__((address_space(1))) unsigned int*)(g),                    \
        (__attribute__((address_space(3))) unsigned int*)(l), 16, 0, 0)

// ============ unified 128x128 GEMM engine, BK=64, dbuf, lane-static =========
// Tile pair per buffer: A[128][64] f16 (16KB) + B[128][64] (16KB) = 32KB.
// LDS rows are 128B; chunk swizzle c ^= row&7 (read) / inverse on gload source.
// MODE 0: proj  C[16384,1536] = xh @ W'  (W' = [Wh;Wl] stacked, virtual K=1024)
// MODE 1: qk    S[b][2048,2048] = Q @ K^T (K=512)
// MODE 2: pv    out[b][2048,512] = P @ V^T (K=2048)
template <int MODE>
__global__ __launch_bounds__(256) void gemmc(
    const _Float16* __restrict__ A, const _Float16* __restrict__ B,
    const float* __restrict__ bq, const float* __restrict__ bk,
    const float* __restrict__ bv,
    _Float16* __restrict__ oq, _Float16* __restrict__ ok, _Float16* __restrict__ ovt,
    float* __restrict__ of, int bat0) {
    __shared__ char sm[2 * 32768];   // buf b: A at b*32768, B at b*32768+16384
    constexpr int T  = (MODE == 0) ? 16 : (MODE == 1) ? 8 : 32;
    constexpr int PA = (MODE == 0) ? 512 : (MODE == 1) ? 512 : 4096;
    constexpr int PB = (MODE == 0) ? 1024 : (MODE == 1) ? 512 : 2048;

    int tid = threadIdx.x, wid = tid >> 6, lane = tid & 63, r = lane & 15, g = lane >> 4;
    int mw = wid >> 1, nw = wid & 1;
    int m0 = blockIdx.x * 128, n0 = blockIdx.y * 128, bz = blockIdx.z;

    const _Float16 *Ab, *Bb;
    if (MODE == 0) {
        Ab = A + (size_t)m0 * 512;
        Bb = B + (size_t)n0 * 1024;
    } else if (MODE == 1) {
        int b = bat0 + bz;
        Ab = A + ((size_t)(b * SEQ) + m0) * 512;
        Bb = B + ((size_t)(b * SEQ) + n0) * 512;
    } else {
        int b = bat0 + bz;
        Ab = A + (size_t)bz * (SEQ * 4096) + (size_t)m0 * 4096;
        Bb = B + (size_t)b * (512 * SEQ) + (size_t)n0 * 2048;
    }

    // ---- lane-static staging addresses (16 chunk-groups of 64 per tile) ----
    const char* gA[4];
    const char* gB[4];
    int ldsw[4];
#pragma unroll
    for (int j = 0; j < 4; ++j) {
        int ci = (j * 4 + wid) * 64 + lane;   // chunk index 0..1023
        int row = ci >> 3, cl = ci & 7;
        int col16 = cl ^ (row & 7);           // inverse swizzle on global source
        gA[j] = (const char*)Ab + (size_t)row * (PA * 2) + col16 * 16;
        gB[j] = (const char*)Bb + (size_t)row * (PB * 2) + col16 * 16;
        ldsw[j] = (j * 4 + wid) * 1024;
    }
    // ---- lane-static fragment read offsets (row stride 128B, swizzled) ----
    int offA[4][2], offB[4][2];
#pragma unroll
    for (int m = 0; m < 4; ++m) {
        int rowA = mw * 64 + m * 16 + r;
        int rowB = nw * 64 + m * 16 + r;
#pragma unroll
        for (int ks = 0; ks < 2; ++ks) {
            offA[m][ks] = rowA * 128 + (((ks * 4 + g) ^ (rowA & 7)) * 16);
            offB[m][ks] = rowB * 128 + (((ks * 4 + g) ^ (rowB & 7)) * 16);
        }
    }

    f32x4 acc[4][4];
#pragma unroll
    for (int m = 0; m < 4; ++m)
#pragma unroll
        for (int n = 0; n < 4; ++n) acc[m][n] = (f32x4)(0.0f);

    // stage tile t into buffer b (8 async 16B loads/thread)
    auto STG = [&](int t, int b) {
        int ka = (MODE == 0) ? ((t & 7) * 128) : (t * 128);   // bytes along k
        int kb = t * 128;
        char* dA = sm + b * 32768;
        char* dB = sm + b * 32768 + 16384;
#pragma unroll
        for (int j = 0; j < 4; ++j) {
            GLOAD_LDS16(gA[j] + ka, dA + ldsw[j]);
            GLOAD_LDS16(gB[j] + kb, dB + ldsw[j]);
        }
    };

    // prologue: tile 0
    STG(0, 0);
    asm volatile("s_waitcnt vmcnt(0)" ::: "memory");
    __builtin_amdgcn_s_barrier();

#pragma unroll
    for (int t = 0; t < T; ++t) {
        const int buf = t & 1;
        if (t + 1 < T) STG(t + 1, buf ^ 1);
        const char* bA = sm + buf * 32768;
        const char* bB = sm + buf * 32768 + 16384;
        h8 af[4][2], bf[4][2];
#pragma unroll
        for (int m = 0; m < 4; ++m)
#pragma unroll
            for (int ks = 0; ks < 2; ++ks) {
                af[m][ks] = *(const h8*)(bA + offA[m][ks]);
                bf[m][ks] = *(const h8*)(bB + offB[m][ks]);
            }
#pragma unroll
        for (int ks = 0; ks < 2; ++ks)
#pragma unroll
            for (int m = 0; m < 4; ++m)
#pragma unroll
                for (int n = 0; n < 4; ++n)
                    acc[m][n] = MFMA16(af[m][ks], bf[n][ks], acc[m][n]);
        if (t + 1 < T) {
            asm volatile("s_waitcnt vmcnt(0)" ::: "memory");   // tile t+1 landed
            __builtin_amdgcn_s_barrier();
        }
    }

    // ---- epilogue ----
    if (MODE == 0) {
        int p = n0 >> 9;
        int ncl = n0 & 511;
        const float* bias = (p == 0) ? bq : (p == 1) ? bk : bv;
#pragma unroll
        for (int n = 0; n < 4; ++n) {
            int col = ncl + nw * 64 + n * 16 + r;
            float bi = bias[col];
#pragma unroll
            for (int m = 0; m < 4; ++m) {
                int grow0 = m0 + mw * 64 + m * 16 + 4 * g;
                if (p == 0) {
                    for (int reg = 0; reg < 4; ++reg)
                        oq[(size_t)(grow0 + reg) * 512 + col] =
                            (_Float16)(acc[m][n][reg] + bi);
                } else if (p == 1) {
                    for (int reg = 0; reg < 4; ++reg)
                        ok[(size_t)(grow0 + reg) * 512 + col] =
                            (_Float16)(acc[m][n][reg] + bi);
                } else {
                    int b = grow0 >> 11, s0 = grow0 & 2047;
                    h4 pv;
                    pv[0] = (_Float16)(acc[m][n][0] + bi);
                    pv[1] = (_Float16)(acc[m][n][1] + bi);
                    pv[2] = (_Float16)(acc[m][n][2] + bi);
                    pv[3] = (_Float16)(acc[m][n][3] + bi);
                    *(h4*)(&ovt[(size_t)b * (512 * 2048) + (size_t)col * 2048 + s0]) = pv;
                }
            }
        }
    } else if (MODE == 1) {
        float* sb = of + (size_t)bz * (SEQ * (size_t)SEQ);
#pragma unroll
        for (int n = 0; n < 4; ++n) {
            int col = n0 + nw * 64 + n * 16 + r;
#pragma unroll
            for (int m = 0; m < 4; ++m) {
                int grow0 = m0 + mw * 64 + m * 16 + 4 * g;
                for (int reg = 0; reg < 4; ++reg)
                    sb[(size_t)(grow0 + reg) * SEQ + col] = acc[m][n][reg];
            }
        }
    } else {
        int b = bat0 + bz;
#pragma unroll
        for (int n = 0; n < 4; ++n) {
            int col = n0 + nw * 64 + n * 16 + r;
#pragma unroll
            for (int m = 0; m < 4; ++m) {
                int grow0 = m0 + mw * 64 + m * 16 + 4 * g;
                for (int reg = 0; reg < 4; ++reg)
                    of[(size_t)(b * SEQ + grow0 + reg) * 512 + col] = acc[m][n][reg];
            }
        }
    }
}

// ---------------- K0a: split W -> f16 hi/lo, stacked-K, transposed ----------
__global__ __launch_bounds__(256) void k0a_splitw(
    const float* __restrict__ Wq, const float* __restrict__ Wk, const float* __restrict__ Wv,
    _Float16* __restrict__ wstk) {
    int idx = blockIdx.x * 256 + threadIdx.x;   // [0, 3*512*512)
    int p = idx >> 18;
    int rem = idx & 262143;
    int k = rem >> 9, n = rem & 511;
    const float* W = (p == 0) ? Wq : (p == 1) ? Wk : Wv;
    float w = W[rem];
    _Float16 h = (_Float16)w;
    size_t base = (size_t)(p * 512 + n) * 1024;
    wstk[base + k] = h;
    wstk[base + 512 + k] = (_Float16)(w - (float)h);
}

// ---------------- K0b: x -> f16 ---------------------------------------------
__global__ __launch_bounds__(256) void k0b_splitx(
    const float* __restrict__ x, _Float16* __restrict__ xh) {
    size_t i = (size_t)(blockIdx.x * 256 + threadIdx.x) * 4;
    float4 v = *(const float4*)(x + i);
    h4 h;
    h[0] = (_Float16)v.x; h[1] = (_Float16)v.y;
    h[2] = (_Float16)v.z; h[3] = (_Float16)v.w;
    *(h4*)(xh + i) = h;
}

// ---------------- K3: row softmax, in-place P(f16) over S(f32) --------------
__global__ __launch_bounds__(256) void k3_softmax(float* __restrict__ sbuf) {
    size_t row = blockIdx.x;
    float* srow = sbuf + row * SEQ;
    int tid = threadIdx.x, lane = tid & 63, wid = tid >> 6;
    float4 v0 = *(const float4*)(srow + tid * 8);
    float4 v1 = *(const float4*)(srow + tid * 8 + 4);
    float m = fmaxf(fmaxf(fmaxf(v0.x, v0.y), fmaxf(v0.z, v0.w)),
                    fmaxf(fmaxf(v1.x, v1.y), fmaxf(v1.z, v1.w)));
    for (int d = 1; d < 64; d <<= 1) m = fmaxf(m, __shfl_xor(m, d));
    __shared__ float red1[4], red2[4];
    if (lane == 0) red1[wid] = m;
    __syncthreads();
    m = fmaxf(fmaxf(red1[0], red1[1]), fmaxf(red1[2], red1[3]));
    float e[8];
    e[0] = __expf(v0.x - m); e[1] = __expf(v0.y - m);
    e[2] = __expf(v0.z - m); e[3] = __expf(v0.w - m);
    e[4] = __expf(v1.x - m); e[5] = __expf(v1.y - m);
    e[6] = __expf(v1.z - m); e[7] = __expf(v1.w - m);
    float s = ((e[0] + e[1]) + (e[2] + e[3])) + ((e[4] + e[5]) + (e[6] + e[7]));
    for (int d = 1; d < 64; d <<= 1) s += __shfl_xor(s, d);
    if (lane == 0) red2[wid] = s;
    __syncthreads();
    s = (red2[0] + red2[1]) + (red2[2] + red2[3]);
    float inv = 1.0f / s;
    h8 ph;
    for (int j = 0; j < 8; ++j) ph[j] = (_Float16)(e[j] * inv);
    *(h8*)((char*)srow + (size_t)tid * 16) = ph;   // P row: first 4KB of S row
}

// ---------------------------------------------------------------------------
extern "C" void kernel_launch(void* const* d_in, const int* in_sizes, int n_in,
                              void* d_out, int out_size, void* d_ws, size_t ws_size,
                              hipStream_t stream) {
    const float* x  = (const float*)d_in[0];
    const float* Wq = (const float*)d_in[1];
    const float* bq = (const float*)d_in[2];
    const float* Wk = (const float*)d_in[3];
    const float* bk = (const float*)d_in[4];
    const float* Wv = (const float*)d_in[5];
    const float* bv = (const float*)d_in[6];
    float* out = (float*)d_out;

    char* ws = (char*)d_ws;
    const size_t QSZ = 16777216;   // 16384*512*2B (also = one batch of S fp32)
    _Float16* wstk = (_Float16*)(ws);                         // 3MB stacked W'
    _Float16* xh = (_Float16*)(ws + 3145728);
    _Float16* qh = (_Float16*)(ws + 3145728 + 1 * QSZ);
    _Float16* kh = (_Float16*)(ws + 3145728 + 2 * QSZ);
    _Float16* vt = (_Float16*)(ws + 3145728 + 3 * QSZ);
    const size_t sbase = 3145728 + 4 * QSZ;          // 70,254,592

    k0a_splitw<<<3072, 256, 0, stream>>>(Wq, Wk, Wv, wstk);
    k0b_splitx<<<8192, 256, 0, stream>>>(x, xh);
    gemmc<0><<<dim3(128, 12), 256, 0, stream>>>(xh, wstk, bq, bk, bv,
                                                qh, kh, vt, nullptr, 0);

    size_t avail = (ws_size > sbase) ? (ws_size - sbase) : 0;
    int chunk = (int)(avail / QSZ);
    if (chunk < 1) chunk = 1;
    if (chunk > 8) chunk = 8;
    float* sc = (float*)(ws + sbase);
    for (int b0 = 0; b0 < 8; b0 += chunk) {
        int nb = (8 - b0 < chunk) ? (8 - b0) : chunk;
        gemmc<1><<<dim3(16, 16, nb), 256, 0, stream>>>(qh, kh, nullptr, nullptr, nullptr,
                                                       nullptr, nullptr, nullptr, sc, b0);
        k3_softmax<<<dim3(nb * SEQ), 256, 0, stream>>>(sc);
        gemmc<2><<<dim3(16, 4, nb), 256, 0, stream>>>((const _Float16*)sc, vt,
                                                      nullptr, nullptr, nullptr,
                                                      nullptr, nullptr, nullptr, out, b0);
    }
}